// Round 3
// baseline (912.908 us; speedup 1.0000x reference)
//
#include <hip/hip_runtime.h>
#include <hip/hip_bf16.h>

// Problem: B=32, R=5, N=1024, D=256, H=256
// out[b,n,h] = sum_d nodes[b,n,d]*w0[h,d]
//            + sum_r (1/c[b,r,n]) * sum_d nodes[b,n,d]*wr[r,h,d]
// c[b,r,n] = sum_j adj[b,r,n,j]  (1 if 0)

#define BB 32
#define RR 5
#define NN 1024
#define DD 256
#define HH 256
#define MM (BB * NN)   // 32768 global rows

typedef __attribute__((ext_vector_type(8))) short short8;
typedef __attribute__((ext_vector_type(4))) float f32x4;

#define GAS(p) ((const __attribute__((address_space(1))) void*)(p))
#define LAS(p) ((__attribute__((address_space(3))) void*)(p))

__device__ __forceinline__ unsigned short f2bf(float f) {
    unsigned int u = __float_as_uint(f);
    unsigned int r = (u + 0x7FFFu + ((u >> 16) & 1u)) >> 16;
    return (unsigned short)r;
}

// Fused prep: rowsum (one wave per adj row) + bf16 conversion of nodes/w0/wr,
// piggybacked grid-stride on the rowsum grid (10240 blocks x 256 thr).
__global__ __launch_bounds__(256) void prep_kernel(
    const float* __restrict__ adj, float* __restrict__ inv_c,
    const float* __restrict__ nodes, unsigned short* __restrict__ nodesb,
    const float* __restrict__ w0, const float* __restrict__ wr,
    unsigned short* __restrict__ wb) {
    const int tid  = threadIdx.x;
    const int lane = tid & 63;

    // --- cvt: nodes (8388608 elems, 4/thread => needs 2097152 threads; grid has 2621440)
    const int gid = blockIdx.x * 256 + tid;
    const int i4  = gid * 4;
    if (i4 < MM * DD) {
        float4 v = *reinterpret_cast<const float4*>(nodes + i4);
        ushort4 o;
        o.x = f2bf(v.x); o.y = f2bf(v.y); o.z = f2bf(v.z); o.w = f2bf(v.w);
        *reinterpret_cast<ushort4*>(nodesb + i4) = o;
    }
    // --- cvt: weights (w0 then wr, 393216 elems total => 98304 threads)
    if (gid < (HH * DD + RR * HH * DD) / 4) {
        const int i = gid * 4;
        float4 v;
        if (i < HH * DD) v = *reinterpret_cast<const float4*>(w0 + i);
        else             v = *reinterpret_cast<const float4*>(wr + (i - HH * DD));
        ushort4 o;
        o.x = f2bf(v.x); o.y = f2bf(v.y); o.z = f2bf(v.z); o.w = f2bf(v.w);
        *reinterpret_cast<ushort4*>(wb + i) = o;
    }

    // --- rowsum: wave per adjacency row (1024 floats)
    const int wave = blockIdx.x * 4 + (tid >> 6);
    const float4* row4 = reinterpret_cast<const float4*>(adj + (size_t)wave * NN);
    float s = 0.f;
#pragma unroll
    for (int i = 0; i < 4; ++i) {
        float4 v = row4[lane + 64 * i];
        s += (v.x + v.y) + (v.z + v.w);
    }
#pragma unroll
    for (int off = 32; off > 0; off >>= 1) s += __shfl_down(s, off, 64);
    if (lane == 0) {
        float c = (s == 0.f) ? 1.f : s;
        inv_c[wave] = 1.f / c;
    }
}

// Fused 6-set GEMM + per-row combine, pipelined K-loop (AITER-style):
// double-buffered LDS, raw s_barrier + fine-grained vmcnt(7), stage(kt+2)
// issued while computing kt so prefetch stays in flight across barriers.
// Block = 256 thr (4 waves). Tile: 64 rows x 64 cols x 6 sets, BK=32.
// LDS per buffer: A 64x32 bf16 (4 KB) + B 6x64x32 bf16 (24 KB) = 28 KB.
__global__ __launch_bounds__(256) void gemm_kernel(
    const unsigned short* __restrict__ nodesb,
    const unsigned short* __restrict__ wb,
    const float* __restrict__ inv_c,
    float* __restrict__ out) {
    __shared__ unsigned short smem[2 * 14336];  // two 28 KB buffers
    __shared__ float s_inv[RR * 64];

    const int tid  = threadIdx.x;
    const int lane = tid & 63;
    const int wv   = tid >> 6;
    const int row_base = blockIdx.x * 64;
    const int col_base = blockIdx.y * 64;
    const int m    = lane & 15;
    const int quad = lane >> 4;

    // staging: 28 x 1KB chunks per buffer, wave wv owns chunks wv*7..wv*7+6
    const unsigned short* gp[7];
    unsigned short*       lp[7];
#pragma unroll
    for (int j = 0; j < 7; ++j) {
        const int c = wv * 7 + j;
        lp[j] = smem + c * 512;
        if (c < 4) {
            const int u   = c * 64 + lane;      // 16B-unit index in A region
            const int row = u >> 2;
            const int kc  = u & 3;
            gp[j] = nodesb + (size_t)(row_base + row) * DD + kc * 8;
        } else {
            const int u    = (c - 4) * 64 + lane;
            const int col6 = u >> 2;            // set*64 + col
            const int kc   = u & 3;
            const int set  = col6 >> 6;
            const int col  = col6 & 63;
            gp[j] = wb + (size_t)(set * HH + col_base + col) * DD + kc * 8;
        }
    }

    f32x4 acc[6][4];
#pragma unroll
    for (int s = 0; s < 6; ++s)
#pragma unroll
        for (int t = 0; t < 4; ++t) acc[s][t] = (f32x4){0.f, 0.f, 0.f, 0.f};

    const int aoff = m * 32 + quad * 8;                     // + t*512 (+buf)
    const int boff = 2048 + (wv * 16 + m) * 32 + quad * 8;  // + s*2048 (+buf)

    // prologue: stage(0) -> buf0, stage(1) -> buf1
#pragma unroll
    for (int j = 0; j < 7; ++j)
        __builtin_amdgcn_global_load_lds(GAS(gp[j]), LAS(lp[j]), 16, 0, 0);
#pragma unroll
    for (int j = 0; j < 7; ++j)
        __builtin_amdgcn_global_load_lds(GAS(gp[j] + 32), LAS(lp[j] + 14336), 16, 0, 0);

#pragma unroll
    for (int kt = 0; kt < 8; ++kt) {
        // wait for own stage(kt) loads (7 newer ones — stage(kt+1) — may remain in flight)
        if (kt < 7) asm volatile("s_waitcnt vmcnt(7)" ::: "memory");
        else        asm volatile("s_waitcnt vmcnt(0)" ::: "memory");
        asm volatile("s_barrier" ::: "memory");   // all waves' stage(kt) landed

        const unsigned short* base = smem + (kt & 1) * 14336;
        short8 afr[4];
#pragma unroll
        for (int t = 0; t < 4; ++t)
            afr[t] = *reinterpret_cast<const short8*>(base + aoff + t * 512);
#pragma unroll
        for (int s = 0; s < 6; ++s) {
            short8 bfr = *reinterpret_cast<const short8*>(base + boff + s * 2048);
#pragma unroll
            for (int t = 0; t < 4; ++t)
                acc[s][t] = __builtin_amdgcn_mfma_f32_16x16x32_bf16(afr[t], bfr, acc[s][t], 0, 0, 0);
        }

        asm volatile("s_barrier" ::: "memory");   // all waves done reading buf[kt&1]
        if (kt < 6) {
#pragma unroll
            for (int j = 0; j < 7; ++j)
                __builtin_amdgcn_global_load_lds(GAS(gp[j] + (kt + 2) * 32),
                                                 LAS(lp[j] + (kt & 1) * 14336), 16, 0, 0);
        }
    }

    // --- epilogue: stage inv_c tile (5 x 64 floats) in LDS
    const int b  = row_base >> 10;
    const int n0 = row_base & (NN - 1);
    __syncthreads();
#pragma unroll
    for (int i = tid; i < RR * 64; i += 256) {
        const int r = i >> 6, nl = i & 63;
        s_inv[i] = inv_c[((size_t)b * RR + r) * NN + n0 + nl];
    }
    __syncthreads();

    const int hcol = col_base + wv * 16 + m;
#pragma unroll
    for (int t = 0; t < 4; ++t) {
#pragma unroll
        for (int i = 0; i < 4; ++i) {
            const int rloc = t * 16 + quad * 4 + i;
            float v = acc[0][t][i];
#pragma unroll
            for (int r = 0; r < RR; ++r)
                v += s_inv[r * 64 + rloc] * acc[r + 1][t][i];
            out[(size_t)(row_base + rloc) * HH + hcol] = v;
        }
    }
}

extern "C" void kernel_launch(void* const* d_in, const int* in_sizes, int n_in,
                              void* d_out, int out_size, void* d_ws, size_t ws_size,
                              hipStream_t stream) {
    const float* nodes = (const float*)d_in[0];  // (B,N,D)
    const float* adj   = (const float*)d_in[1];  // (B,R,N,N)
    const float* w0    = (const float*)d_in[2];  // (H,D)
    const float* wr    = (const float*)d_in[3];  // (R,H,D)
    float* out = (float*)d_out;                  // (B,N,H)

    // Workspace layout
    unsigned short* nodesb = (unsigned short*)d_ws;                                  // M*D bf16
    unsigned short* wb     = (unsigned short*)((char*)d_ws + (size_t)MM * DD * 2);   // 6*H*D bf16
    float*          inv_c  = (float*)((char*)d_ws + (size_t)MM * DD * 2 + (size_t)6 * HH * DD * 2);

    prep_kernel<<<(BB * RR * NN) / 4, 256, 0, stream>>>(adj, inv_c, nodes, nodesb, w0, wr, wb);

    gemm_kernel<<<dim3(MM / 64, HH / 64), 256, 0, stream>>>(nodesb, wb, inv_c, out);
}